// Round 4
// baseline (226.572 us; speedup 1.0000x reference)
//
#include <hip/hip_runtime.h>
#include <hip/hip_bf16.h>

#define RES 300
#define NPLANE (RES * RES)   // 90000
#define NC_A 48
#define APP_DIM 27
#define KDIM 144             // 3 * NC_A
#define KS 168               // prod LDS row stride in shorts (336 B, 16B-aligned)

#define PT_TILES 1407        // ceil(90000 / 64) p-tiles per plane
#define NPB2 (3 * PT_TILES)  // 4221 plane-transpose blocks

// bf16 (packed in uint halves) -> f32
__device__ __forceinline__ float bf_lo(unsigned int u) { return __uint_as_float(u << 16); }
__device__ __forceinline__ float bf_hi(unsigned int u) { return __uint_as_float(u & 0xffff0000u); }

// ---------------------------------------------------------------------------
// Unified prep kernel (unchanged — passing since R1).
// ---------------------------------------------------------------------------
__global__ __launch_bounds__(256) void prep(
    const float* __restrict__ plane, const float* __restrict__ line,
    const float* __restrict__ W,
    unsigned int* __restrict__ TpUo, unsigned int* __restrict__ TlP,
    __hip_bfloat16* __restrict__ Wg) {
  __shared__ __align__(16) unsigned int lt[64 * 65];
  const int blk = blockIdx.x;
  const int tid = threadIdx.x;

  if (blk < NPB2) {
    const int i  = blk / PT_TILES;
    const int t0 = blk - i * PT_TILES;
    const int p0 = t0 * 64;

    const int cb   = (tid >> 4) * 4;
    const int poff = (tid & 15) * 4;
    const bool ok  = (p0 + poff) < NPLANE;

    const float* src = plane + (size_t)(i * 64 + cb) * NPLANE + p0 + poff;
    float4 v0, v1, v2, v3;
    v0 = v1 = v2 = v3 = make_float4(0.f, 0.f, 0.f, 0.f);
    if (ok) {
      v0 = *(const float4*)(src);
      v1 = *(const float4*)(src + NPLANE);
      v2 = *(const float4*)(src + 2 * NPLANE);
      v3 = *(const float4*)(src + 3 * NPLANE);
    }
    const int col = (tid >> 4) * 2;
    const float* f0 = &v0.x; const float* f1 = &v1.x;
    const float* f2 = &v2.x; const float* f3 = &v3.x;
    #pragma unroll
    for (int j = 0; j < 4; ++j) {
      __hip_bfloat162 ha, hb;
      ha.x = __float2bfloat16(f0[j]);
      ha.y = __float2bfloat16(f1[j]);
      hb.x = __float2bfloat16(f2[j]);
      hb.y = __float2bfloat16(f3[j]);
      uint2 u;
      u.x = *(unsigned int*)&ha;
      u.y = *(unsigned int*)&hb;
      *(uint2*)&lt[(poff + j) * 34 + col] = u;
    }
    __syncthreads();
    #pragma unroll
    for (int pass = 0; pass < 2; ++pass) {
      int p  = (tid >> 3) + pass * 32;
      int c4 = (tid & 7) * 4;
      if (p0 + p < NPLANE) {
        uint2 a = *(const uint2*)&lt[p * 34 + c4];
        uint2 b = *(const uint2*)&lt[p * 34 + c4 + 2];
        uint4 w; w.x = a.x; w.y = a.y; w.z = b.x; w.w = b.y;
        *(uint4*)&TpUo[((size_t)(i * NPLANE + p0 + p)) * 32 + c4] = w;
      }
    }
  } else if (blk < NPB2 + 15) {
    const int b  = blk - NPB2;
    const int i  = b / 5;
    const int y0 = (b % 5) * 64;
    const int yl = tid & 63;
    const int cq = tid >> 6;
    #pragma unroll
    for (int k = 0; k < 16; ++k) {
      int c = cq * 16 + k;
      int y = y0 + yl;
      float a = 0.f, bv = 0.f;
      if (y < RES) {
        const float* row = line + (i * 64 + c) * RES;
        a  = row[y];
        bv = row[min(y + 1, RES - 1)];
      }
      __hip_bfloat162 h;
      h.x = __float2bfloat16(a);
      h.y = __float2bfloat16(bv);
      lt[yl * 65 + c] = *(unsigned int*)&h;
    }
    __syncthreads();
    #pragma unroll
    for (int k = 0; k < 16; ++k) {
      int ylc = k * 4 + cq;
      int c   = tid & 63;
      int y   = y0 + ylc;
      if (y < RES) TlP[((size_t)i * RES + y) * 64 + c] = lt[ylc * 65 + c];
    }
  } else {
    for (int idx = tid; idx < 2 * 5 * 64 * 8; idx += 256) {
      int j    = idx & 7;
      int lane = (idx >> 3) & 63;
      int kt   = (idx >> 9) % 5;
      int tile = idx / (5 * 64 * 8);
      int n = tile * 16 + (lane & 15);
      int k = kt * 32 + (lane >> 4) * 8 + j;
      float v = (n < APP_DIM && k < KDIM) ? W[n * KDIM + k] : 0.f;
      Wg[idx] = __float2bfloat16(v);
    }
  }
}

// ---------------------------------------------------------------------------
// Main kernel: fused gather + blend + sigma + MFMA projection.
// Channel-QUAD scheme (R3, passing) + explicit depth-2 software pipeline:
// two NAMED register sets ga/gb alternate, fully unrolled, no conditionals,
// no copies; sched_barrier(0) after each prefetch batch stops the compiler
// from sinking loads below the following blend (which defeated R1's
// pipeline — VGPR count is the verification: expect ~85-100, was 40).
// LDS = 21504 (prod) + 4608 (cw) = 26112 B.
// ---------------------------------------------------------------------------
typedef __attribute__((ext_vector_type(8))) short short8;
typedef __attribute__((ext_vector_type(4))) float f32x4;

struct G {
  uint2 u00[3], u01[3], u10[3], u11[3];
  uint4 ul[3];
};

__device__ __forceinline__ void load_g(
    const float* __restrict__ cp, const unsigned int* __restrict__ TpU,
    const unsigned int* __restrict__ TlP, int cq2, int c4, G& g) {
  #pragma unroll
  for (int i = 0; i < 3; ++i) {
    int pk   = __float_as_int(cp[i * 6]);
    int cell = pk & 0x7FFFF;
    int lidx = pk >> 19;
    int bidx = cell * 32 + cq2;                 // uint index into TpU
    g.u00[i] = *(const uint2*)&TpU[bidx];
    g.u01[i] = *(const uint2*)&TpU[bidx + 32];
    g.u10[i] = *(const uint2*)&TpU[bidx + RES * 32];
    g.u11[i] = *(const uint2*)&TpU[bidx + RES * 32 + 32];
    g.ul[i]  = *(const uint4*)&TlP[(lidx << 6) + c4];
  }
}

__device__ __forceinline__ float blend_g(
    const float* __restrict__ cp, const G& g, int cq, int c4,
    __hip_bfloat16* __restrict__ prodRow) {
  float dsum = 0.f;
  #pragma unroll
  for (int i = 0; i < 3; ++i) {
    float w00 = cp[i * 6 + 1], w01 = cp[i * 6 + 2];
    float w10 = cp[i * 6 + 3], w11 = cp[i * 6 + 4];
    float lw  = cp[i * 6 + 5];
    // dword 0: channels 4cq, 4cq+1
    {
      float pf_l = w00 * bf_lo(g.u00[i].x) + w01 * bf_lo(g.u01[i].x) +
                   w10 * bf_lo(g.u10[i].x) + w11 * bf_lo(g.u11[i].x);
      float pf_h = w00 * bf_hi(g.u00[i].x) + w01 * bf_hi(g.u01[i].x) +
                   w10 * bf_hi(g.u10[i].x) + w11 * bf_hi(g.u11[i].x);
      float lal = bf_lo(g.ul[i].x), lbl = bf_hi(g.ul[i].x);
      float lah = bf_lo(g.ul[i].y), lbh = bf_hi(g.ul[i].y);
      float lf_l = lal + lw * (lbl - lal);
      float lf_h = lah + lw * (lbh - lah);
      float prl = pf_l * lf_l, prh = pf_h * lf_h;
      if (cq < 12) {
        __hip_bfloat162 h;
        h.x = __float2bfloat16(prl);
        h.y = __float2bfloat16(prh);
        *(unsigned int*)&prodRow[i * NC_A + c4] = *(unsigned int*)&h;
      } else {
        dsum += prl + prh;
      }
    }
    // dword 1: channels 4cq+2, 4cq+3
    {
      float pf_l = w00 * bf_lo(g.u00[i].y) + w01 * bf_lo(g.u01[i].y) +
                   w10 * bf_lo(g.u10[i].y) + w11 * bf_lo(g.u11[i].y);
      float pf_h = w00 * bf_hi(g.u00[i].y) + w01 * bf_hi(g.u01[i].y) +
                   w10 * bf_hi(g.u10[i].y) + w11 * bf_hi(g.u11[i].y);
      float lal = bf_lo(g.ul[i].z), lbl = bf_hi(g.ul[i].z);
      float lah = bf_lo(g.ul[i].w), lbh = bf_hi(g.ul[i].w);
      float lf_l = lal + lw * (lbl - lal);
      float lf_h = lah + lw * (lbh - lah);
      float prl = pf_l * lf_l, prh = pf_h * lf_h;
      if (cq < 12) {
        __hip_bfloat162 h;
        h.x = __float2bfloat16(prl);
        h.y = __float2bfloat16(prh);
        *(unsigned int*)&prodRow[i * NC_A + c4 + 2] = *(unsigned int*)&h;
      } else {
        dsum += prl + prh;
      }
    }
  }
  return dsum;
}

__global__ __launch_bounds__(256, 5) void tensorf_main(
    const float* __restrict__ xyz, const unsigned int* __restrict__ TpU,
    const unsigned int* __restrict__ TlP, const __hip_bfloat16* __restrict__ Wg,
    float* __restrict__ out, int n_total) {
  __shared__ __hip_bfloat16 prod[64 * KS];
  __shared__ float cw[64 * 18];

  const int tid  = threadIdx.x;
  const int lane = tid & 63;
  const int wave = tid >> 6;
  const int n0   = blockIdx.x * 64;

  // zero prod k-pad [144,168)
  for (int j = tid; j < 64 * 12; j += 256) {
    int s = j / 12, kk = (j % 12) * 2;
    *(unsigned int*)&prod[s * KS + KDIM + kk] = 0u;
  }

  // Phase 0: per-sample precompute (exact passing R0/R3 form).
  if (tid < 64) {
    int n = min(n0 + tid, n_total - 1);
    float crd[3] = {xyz[3 * n], xyz[3 * n + 1], xyz[3 * n + 2]};
    const int m0s[3] = {0, 0, 1}, m1s[3] = {1, 2, 2}, vms[3] = {2, 1, 0};
    float* c = &cw[tid * 18];
    #pragma unroll
    for (int i = 0; i < 3; ++i) {
      float ix = fminf(fmaxf((crd[m0s[i]] + 1.f) * 149.5f, 0.f), 299.f);
      float iy = fminf(fmaxf((crd[m1s[i]] + 1.f) * 149.5f, 0.f), 299.f);
      float ly = fminf(fmaxf((crd[vms[i]] + 1.f) * 149.5f, 0.f), 299.f);
      float x0f = fminf(floorf(ix), 298.f);
      float y0f = fminf(floorf(iy), 298.f);
      float l0f = fminf(floorf(ly), 298.f);
      float wx = ix - x0f, wy = iy - y0f, lwy = ly - l0f;
      int cell = i * NPLANE + (int)y0f * RES + (int)x0f;   // < 2^19
      int lidx = i * RES + (int)l0f;                       // < 2^10
      c[i * 6 + 0] = __int_as_float(cell | (lidx << 19));
      c[i * 6 + 1] = (1.f - wx) * (1.f - wy);
      c[i * 6 + 2] = wx * (1.f - wy);
      c[i * 6 + 3] = (1.f - wx) * wy;
      c[i * 6 + 4] = wx * wy;
      c[i * 6 + 5] = lwy;
    }
  }
  __syncthreads();

  // Phase 1: depth-2 pipelined; 4 samples/wave-iter, 4 channels/lane
  const int cq  = lane & 15;    // channel quad -> channels 4cq..4cq+3
  const int sq  = lane >> 4;    // sample slot within iteration group
  const int c4  = cq * 4;
  const int cq2 = cq * 2;
  const int sb  = wave * 16 + sq;       // base sample slot, +4 per iteration

  const float* cp0 = &cw[(sb + 0) * 18];
  const float* cp1 = &cw[(sb + 4) * 18];
  const float* cp2 = &cw[(sb + 8) * 18];
  const float* cp3 = &cw[(sb + 12) * 18];

  G ga, gb;
  float dsum;
  int n;

  // prologue: fill both stages (30 VMEM in flight)
  load_g(cp0, TpU, TlP, cq2, c4, ga);
  load_g(cp1, TpU, TlP, cq2, c4, gb);
  __builtin_amdgcn_sched_barrier(0);

  // it 0: blend ga, prefetch it2 into ga after use
  dsum = blend_g(cp0, ga, cq, c4, &prod[(sb + 0) * KS]);
  dsum += __shfl_xor(dsum, 1);
  dsum += __shfl_xor(dsum, 2);
  n = n0 + sb + 0;
  if (cq == 12 && n < n_total) out[n] = dsum;
  load_g(cp2, TpU, TlP, cq2, c4, ga);
  __builtin_amdgcn_sched_barrier(0);

  // it 1: blend gb, prefetch it3 into gb after use
  dsum = blend_g(cp1, gb, cq, c4, &prod[(sb + 4) * KS]);
  dsum += __shfl_xor(dsum, 1);
  dsum += __shfl_xor(dsum, 2);
  n = n0 + sb + 4;
  if (cq == 12 && n < n_total) out[n] = dsum;
  load_g(cp3, TpU, TlP, cq2, c4, gb);
  __builtin_amdgcn_sched_barrier(0);

  // it 2: blend ga
  dsum = blend_g(cp2, ga, cq, c4, &prod[(sb + 8) * KS]);
  dsum += __shfl_xor(dsum, 1);
  dsum += __shfl_xor(dsum, 2);
  n = n0 + sb + 8;
  if (cq == 12 && n < n_total) out[n] = dsum;

  // it 3: blend gb
  dsum = blend_g(cp3, gb, cq, c4, &prod[(sb + 12) * KS]);
  dsum += __shfl_xor(dsum, 1);
  dsum += __shfl_xor(dsum, 2);
  n = n0 + sb + 12;
  if (cq == 12 && n < n_total) out[n] = dsum;

  __syncthreads();

  // Phase 2: app = prod(64x144) @ W^T via mfma 16x16x32 bf16, B from Wg
  const int srow = lane & 15, quad = lane >> 4;
  f32x4 acc0 = {0.f, 0.f, 0.f, 0.f}, acc1 = {0.f, 0.f, 0.f, 0.f};
  const short* prodS = (const short*)prod;
  const short* WgS   = (const short*)Wg;
  const int arow = (wave * 16 + srow) * KS;
  #pragma unroll
  for (int kt = 0; kt < 5; ++kt) {
    short8 a  = *(const short8*)&prodS[arow + kt * 32 + quad * 8];
    short8 b0 = *(const short8*)&WgS[(kt * 64 + lane) * 8];
    short8 b1 = *(const short8*)&WgS[((5 + kt) * 64 + lane) * 8];
    acc0 = __builtin_amdgcn_mfma_f32_16x16x32_bf16(a, b0, acc0, 0, 0, 0);
    acc1 = __builtin_amdgcn_mfma_f32_16x16x32_bf16(a, b1, acc1, 0, 0, 0);
  }
  // C/D layout: col(d) = lane&15, row(sample) = quad*4 + reg
  float* outApp = out + n_total;
  #pragma unroll
  for (int r = 0; r < 4; ++r) {
    int nn = n0 + wave * 16 + quad * 4 + r;
    if (nn < n_total) {
      outApp[(size_t)nn * APP_DIM + srow] = acc0[r];
      if (srow < APP_DIM - 16)
        outApp[(size_t)nn * APP_DIM + 16 + srow] = acc1[r];
    }
  }
}

// ---------------------------------------------------------------------------
extern "C" void kernel_launch(void* const* d_in, const int* in_sizes, int n_in,
                              void* d_out, int out_size, void* d_ws, size_t ws_size,
                              hipStream_t stream) {
  const float* xyz   = (const float*)d_in[0];
  const float* plane = (const float*)d_in[1];
  const float* line  = (const float*)d_in[2];
  const float* W     = (const float*)d_in[3];
  float* out = (float*)d_out;
  const int N = in_sizes[0] / 3;

  char* ws = (char*)d_ws;
  __hip_bfloat16* Tp  = (__hip_bfloat16*)ws;                        // 34,560,000 B
  unsigned int*   TlP = (unsigned int*)(ws + 34560000);             //    230,400 B
  __hip_bfloat16* Wg  = (__hip_bfloat16*)(ws + 34560000 + 230400);  //     10,240 B

  prep<<<NPB2 + 16, 256, 0, stream>>>(plane, line, W, (unsigned int*)Tp, TlP, Wg);
  tensorf_main<<<(N + 63) / 64, 256, 0, stream>>>(
      xyz, (const unsigned int*)Tp, TlP, Wg, out, N);
}